// Round 4
// baseline (699.423 us; speedup 1.0000x reference)
//
#include <hip/hip_runtime.h>
#include <hip/hip_bf16.h>
#include <hip/hip_fp16.h>

#define BS 256

__device__ __forceinline__ void unpack8(uint4 u, float* f) {
    const __half2* h = (const __half2*)&u;
    float2 t;
    t = __half22float2(h[0]); f[0] = t.x; f[1] = t.y;
    t = __half22float2(h[1]); f[2] = t.x; f[3] = t.y;
    t = __half22float2(h[2]); f[4] = t.x; f[5] = t.y;
    t = __half22float2(h[3]); f[6] = t.x; f[7] = t.y;
}

__device__ __forceinline__ uint4 pack8(const float* f) {
    union { uint4 u; __half2 h[4]; } v;
    v.h[0] = __floats2half2_rn(f[0], f[1]);
    v.h[1] = __floats2half2_rn(f[2], f[3]);
    v.h[2] = __floats2half2_rn(f[4], f[5]);
    v.h[3] = __floats2half2_rn(f[6], f[7]);
    return v.u;
}

// ---------------------------------------------------------------------------
// Kernel 1: token histogram -> masked mean embed -> fused X@w1+b1 -> M [N,16]
// ---------------------------------------------------------------------------
__global__ void encode_kernel(const int* __restrict__ seq,
                              const float* __restrict__ xcov,
                              const float* __restrict__ embed,   // 6x16 f32
                              const float* __restrict__ w1,      // 17x16 f32
                              const float* __restrict__ b1,      // 16 f32
                              float* __restrict__ M, int N) {
    __shared__ float sE[96];
    __shared__ float sW[272];
    __shared__ float sB[16];
    int tid = threadIdx.x;
    for (int i = tid; i < 96; i += BS) sE[i] = embed[i];
    for (int i = tid; i < 272; i += BS) sW[i] = w1[i];
    if (tid < 16) sB[tid] = b1[tid];
    __syncthreads();
    int n = blockIdx.x * BS + tid;
    if (n >= N) return;

    const int4* t4 = (const int4*)(seq + (size_t)n * 64);
    int c1 = 0, c2 = 0, c3 = 0, c4 = 0, c5 = 0;
#pragma unroll
    for (int i = 0; i < 16; i++) {
        int4 v = t4[i];
        c1 += (v.x == 1) + (v.y == 1) + (v.z == 1) + (v.w == 1);
        c2 += (v.x == 2) + (v.y == 2) + (v.z == 2) + (v.w == 2);
        c3 += (v.x == 3) + (v.y == 3) + (v.z == 3) + (v.w == 3);
        c4 += (v.x == 4) + (v.y == 4) + (v.z == 4) + (v.w == 4);
        c5 += (v.x == 5) + (v.y == 5) + (v.z == 5) + (v.w == 5);
    }
    float f1 = (float)c1, f2 = (float)c2, f3 = (float)c3, f4 = (float)c4, f5 = (float)c5;
    float tot = f1 + f2 + f3 + f4 + f5;
    float inv = 1.0f / fmaxf(tot, 1.0f);

    float h[16];
#pragma unroll
    for (int j = 0; j < 16; j++)
        h[j] = (f1 * sE[16 + j] + f2 * sE[32 + j] + f3 * sE[48 + j] +
                f4 * sE[64 + j] + f5 * sE[80 + j]) * inv;

    float xc = xcov[n];
    float o[16];
#pragma unroll
    for (int j = 0; j < 16; j++) o[j] = sB[j] + xc * sW[256 + j];
#pragma unroll
    for (int k = 0; k < 16; k++) {
        float hk = h[k];
#pragma unroll
        for (int j = 0; j < 16; j++) o[j] += hk * sW[k * 16 + j];
    }
    float4* mr = (float4*)(M + (size_t)n * 16);
    mr[0] = make_float4(o[0], o[1], o[2], o[3]);
    mr[1] = make_float4(o[4], o[5], o[6], o[7]);
    mr[2] = make_float4(o[8], o[9], o[10], o[11]);
    mr[3] = make_float4(o[12], o[13], o[14], o[15]);
}

// ---------------------------------------------------------------------------
// Kernel 2: prep — single pass over edges: validity, degree, compact list
// ---------------------------------------------------------------------------
__global__ void prep_kernel(const int* __restrict__ ei,
                            const int* __restrict__ batch,
                            float* __restrict__ deg,
                            int2* __restrict__ list,
                            int* __restrict__ counter, int E) {
    int e = blockIdx.x * BS + threadIdx.x;
    if (e >= E) return;
    int s = ei[e];
    int d = ei[E + e];
    if (batch[s] == batch[d]) {
        atomicAdd(&deg[s], 1.0f);
        int pos = atomicAdd(counter, 1);
        list[pos] = make_int2(s, d);
    }
}

// ---------------------------------------------------------------------------
// Kernel 3: dinv = (deg + 1 + 1e-8)^-1/2, in place
// ---------------------------------------------------------------------------
__global__ void dinv_kernel(float* __restrict__ dd, int N) {
    int n = blockIdx.x * BS + threadIdx.x;
    if (n >= N) return;
    float dg = dd[n] + 1.0f + 1e-8f;
    dd[n] = 1.0f / sqrtf(dg);
}

// ---------------------------------------------------------------------------
// Kernel 4: message scatter over COMPACT list: agg[s] += dinv[d] * M[d]
// ---------------------------------------------------------------------------
__global__ void agg_list_kernel(const int2* __restrict__ list,
                                const int* __restrict__ counter,
                                const float* __restrict__ dinv,
                                const float* __restrict__ M,
                                float* __restrict__ agg) {
    int cnt = *counter;
    for (int i = blockIdx.x * BS + threadIdx.x; i < cnt; i += gridDim.x * BS) {
        int2 p = list[i];
        float c = dinv[p.y];
        const float4* m4 = (const float4*)(M + (size_t)p.y * 16);
        float4 v0 = m4[0], v1 = m4[1], v2 = m4[2], v3 = m4[3];
        float* a = agg + (size_t)p.x * 16;
        atomicAdd(a + 0,  c * v0.x); atomicAdd(a + 1,  c * v0.y);
        atomicAdd(a + 2,  c * v0.z); atomicAdd(a + 3,  c * v0.w);
        atomicAdd(a + 4,  c * v1.x); atomicAdd(a + 5,  c * v1.y);
        atomicAdd(a + 6,  c * v1.z); atomicAdd(a + 7,  c * v1.w);
        atomicAdd(a + 8,  c * v2.x); atomicAdd(a + 9,  c * v2.y);
        atomicAdd(a + 10, c * v2.z); atomicAdd(a + 11, c * v2.w);
        atomicAdd(a + 12, c * v3.x); atomicAdd(a + 13, c * v3.y);
        atomicAdd(a + 14, c * v3.z); atomicAdd(a + 15, c * v3.w);
    }
}

// ---------------------------------------------------------------------------
// Kernel 5: H1 = relu(dinv*(agg + dinv*M)); M <- H1@w2+b2 (in place); agg <- 0
// ---------------------------------------------------------------------------
__global__ void finalize1_kernel(const float* __restrict__ dinv,
                                 float* __restrict__ M,
                                 float* __restrict__ agg,
                                 const float* __restrict__ w2,
                                 const float* __restrict__ b2, int N) {
    __shared__ float sW[256];
    __shared__ float sB[16];
    int tid = threadIdx.x;
    for (int i = tid; i < 256; i += BS) sW[i] = w2[i];
    if (tid < 16) sB[tid] = b2[tid];
    __syncthreads();
    int n = blockIdx.x * BS + tid;
    if (n >= N) return;
    float di = dinv[n];
    float4* mr = (float4*)(M + (size_t)n * 16);
    float4* ar = (float4*)(agg + (size_t)n * 16);
    float m[16], a[16];
    float4 t;
    t = mr[0]; m[0]=t.x; m[1]=t.y; m[2]=t.z; m[3]=t.w;
    t = mr[1]; m[4]=t.x; m[5]=t.y; m[6]=t.z; m[7]=t.w;
    t = mr[2]; m[8]=t.x; m[9]=t.y; m[10]=t.z; m[11]=t.w;
    t = mr[3]; m[12]=t.x; m[13]=t.y; m[14]=t.z; m[15]=t.w;
    t = ar[0]; a[0]=t.x; a[1]=t.y; a[2]=t.z; a[3]=t.w;
    t = ar[1]; a[4]=t.x; a[5]=t.y; a[6]=t.z; a[7]=t.w;
    t = ar[2]; a[8]=t.x; a[9]=t.y; a[10]=t.z; a[11]=t.w;
    t = ar[3]; a[12]=t.x; a[13]=t.y; a[14]=t.z; a[15]=t.w;
    // re-zero agg for layer 2
    float4 z = make_float4(0.f, 0.f, 0.f, 0.f);
    ar[0] = z; ar[1] = z; ar[2] = z; ar[3] = z;

    float h[16];
#pragma unroll
    for (int j = 0; j < 16; j++) h[j] = fmaxf(di * (a[j] + di * m[j]), 0.0f);

    float o[16];
#pragma unroll
    for (int j = 0; j < 16; j++) o[j] = sB[j];
#pragma unroll
    for (int k = 0; k < 16; k++) {
        float hk = h[k];
#pragma unroll
        for (int j = 0; j < 16; j++) o[j] += hk * sW[k * 16 + j];
    }
    mr[0] = make_float4(o[0], o[1], o[2], o[3]);
    mr[1] = make_float4(o[4], o[5], o[6], o[7]);
    mr[2] = make_float4(o[8], o[9], o[10], o[11]);
    mr[3] = make_float4(o[12], o[13], o[14], o[15]);
}

// ---------------------------------------------------------------------------
// Kernel 6: H2 = relu(dinv*(agg + dinv*M)); P = H2@we1[0:16]; Q = H2@we1[16:32]
// P, Q stored as f16 rows (32 B) for L2-resident gathers in edge MLP.
// ---------------------------------------------------------------------------
__global__ void finalize2_pq_kernel(const float* __restrict__ dinv,
                                    const float* __restrict__ M,
                                    const float* __restrict__ agg,
                                    const float* __restrict__ we1,  // 37x16
                                    ushort* __restrict__ Pf,
                                    ushort* __restrict__ Qf, int N) {
    __shared__ float sW[512];   // we1 rows 0..31
    int tid = threadIdx.x;
    for (int i = tid; i < 512; i += BS) sW[i] = we1[i];
    __syncthreads();
    int n = blockIdx.x * BS + tid;
    if (n >= N) return;
    float di = dinv[n];
    const float4* mr = (const float4*)(M + (size_t)n * 16);
    const float4* ar = (const float4*)(agg + (size_t)n * 16);
    float h[16];
#pragma unroll
    for (int q = 0; q < 4; q++) {
        float4 m = mr[q], a = ar[q];
        h[q*4+0] = fmaxf(di * (a.x + di * m.x), 0.0f);
        h[q*4+1] = fmaxf(di * (a.y + di * m.y), 0.0f);
        h[q*4+2] = fmaxf(di * (a.z + di * m.z), 0.0f);
        h[q*4+3] = fmaxf(di * (a.w + di * m.w), 0.0f);
    }
    float p[16], q[16];
#pragma unroll
    for (int j = 0; j < 16; j++) { p[j] = 0.f; q[j] = 0.f; }
#pragma unroll
    for (int k = 0; k < 16; k++) {
        float hk = h[k];
#pragma unroll
        for (int j = 0; j < 16; j++) {
            p[j] += hk * sW[k * 16 + j];
            q[j] += hk * sW[(16 + k) * 16 + j];
        }
    }
    uint4* pr = (uint4*)(Pf + (size_t)n * 16);
    pr[0] = pack8(p);
    pr[1] = pack8(p + 8);
    uint4* qr = (uint4*)(Qf + (size_t)n * 16);
    qr[0] = pack8(q);
    qr[1] = pack8(q + 8);
}

// ---------------------------------------------------------------------------
// Kernel 7: edge MLP via precomputed P/Q:
//   acc = P[s] + Q[d] + ea@C + be1 ; logit = relu(acc)@we2 + be2
// ---------------------------------------------------------------------------
__global__ void edge_mlp_kernel(const int* __restrict__ ei,
                                const ushort* __restrict__ Pf,
                                const ushort* __restrict__ Qf,
                                const float* __restrict__ eattr,   // E x 5 f32
                                const float* __restrict__ we1,     // 37x16 f32
                                const float* __restrict__ be1,     // 16
                                const float* __restrict__ we2,     // 16
                                const float* __restrict__ be2,     // 1
                                float* __restrict__ out, int E) {
    __shared__ float sC[80];   // we1 rows 32..36 (edge-attr block)
    __shared__ float sB[16];
    __shared__ float sV[16];
    __shared__ float sb2;
    int tid = threadIdx.x;
    if (tid < 80) sC[tid] = we1[512 + tid];
    if (tid < 16) { sB[tid] = be1[tid]; sV[tid] = we2[tid]; }
    if (tid == 0) sb2 = be2[0];
    __syncthreads();
    int e = blockIdx.x * BS + tid;
    if (e >= E) return;
    int s = ei[e];
    int d = ei[E + e];
    const uint4* pr = (const uint4*)(Pf + (size_t)s * 16);
    const uint4* qr = (const uint4*)(Qf + (size_t)d * 16);
    uint4 pa = pr[0], pb = pr[1];
    uint4 qa = qr[0], qb = qr[1];
    const float* ea = eattr + (size_t)e * 5;
    float a0 = ea[0], a1 = ea[1], a2 = ea[2], a3 = ea[3], a4 = ea[4];

    float p[16], q[16];
    unpack8(pa, p); unpack8(pb, p + 8);
    unpack8(qa, q); unpack8(qb, q + 8);

    float lg = sb2;
#pragma unroll
    for (int j = 0; j < 16; j++) {
        float acc = sB[j] + p[j] + q[j] +
                    a0 * sC[j] + a1 * sC[16 + j] + a2 * sC[32 + j] +
                    a3 * sC[48 + j] + a4 * sC[64 + j];
        lg += fmaxf(acc, 0.0f) * sV[j];
    }
    out[e] = lg;
}

// ---------------------------------------------------------------------------
extern "C" void kernel_launch(void* const* d_in, const int* in_sizes, int n_in,
                              void* d_out, int out_size, void* d_ws, size_t ws_size,
                              hipStream_t stream) {
    const int* seq     = (const int*)d_in[0];
    const float* xcov  = (const float*)d_in[1];
    const int* ei      = (const int*)d_in[2];
    const float* eattr = (const float*)d_in[3];
    const int* batch   = (const int*)d_in[4];
    const float* embed = (const float*)d_in[5];
    const float* w1    = (const float*)d_in[6];
    const float* b1    = (const float*)d_in[7];
    const float* w2    = (const float*)d_in[8];
    const float* b2    = (const float*)d_in[9];
    const float* we1   = (const float*)d_in[10];
    const float* be1   = (const float*)d_in[11];
    const float* we2   = (const float*)d_in[12];
    const float* be2   = (const float*)d_in[13];
    float* out         = (float*)d_out;   // fp32 output

    int N = in_sizes[1];
    int E = in_sizes[2] / 2;

    char* ws = (char*)d_ws;
    size_t off = 0;
    auto alloc = [&](size_t bytes) -> void* {
        void* p = ws + off;
        off += (bytes + 255) & ~(size_t)255;
        return p;
    };
    float* dinv  = (float*)alloc((size_t)N * sizeof(float));       // deg then dinv
    float* M     = (float*)alloc((size_t)N * 16 * sizeof(float));
    float* agg   = (float*)alloc((size_t)N * 16 * sizeof(float));
    ushort* Pf   = (ushort*)alloc((size_t)N * 16 * sizeof(ushort));
    ushort* Qf   = (ushort*)alloc((size_t)N * 16 * sizeof(ushort));
    int* counter = (int*)alloc(sizeof(int));
    int2* list   = (int2*)alloc((size_t)E * sizeof(int2));         // worst case

    hipMemsetAsync(dinv, 0, (size_t)N * sizeof(float), stream);
    hipMemsetAsync(agg, 0, (size_t)N * 16 * sizeof(float), stream);
    hipMemsetAsync(counter, 0, sizeof(int), stream);

    int gn = (N + BS - 1) / BS;
    int ge = (E + BS - 1) / BS;

    encode_kernel<<<gn, BS, 0, stream>>>(seq, xcov, embed, w1, b1, M, N);
    prep_kernel<<<ge, BS, 0, stream>>>(ei, batch, dinv, list, counter, E);
    dinv_kernel<<<gn, BS, 0, stream>>>(dinv, N);
    agg_list_kernel<<<256, BS, 0, stream>>>(list, counter, dinv, M, agg);
    finalize1_kernel<<<gn, BS, 0, stream>>>(dinv, M, agg, w2, b2, N);
    agg_list_kernel<<<256, BS, 0, stream>>>(list, counter, dinv, M, agg);
    finalize2_pq_kernel<<<gn, BS, 0, stream>>>(dinv, M, agg, we1, Pf, Qf, N);
    edge_mlp_kernel<<<ge, BS, 0, stream>>>(ei, Pf, Qf, eattr, we1, be1, we2, be2, out, E);
}

// Round 5
// 379.202 us; speedup vs baseline: 1.8445x; 1.8445x over previous
//
#include <hip/hip_runtime.h>
#include <hip/hip_bf16.h>
#include <hip/hip_fp16.h>

#define BS 256
#define CHUNK 4096   // edges per block in prep (16 per thread)

__device__ __forceinline__ void unpack8(uint4 u, float* f) {
    const __half2* h = (const __half2*)&u;
    float2 t;
    t = __half22float2(h[0]); f[0] = t.x; f[1] = t.y;
    t = __half22float2(h[1]); f[2] = t.x; f[3] = t.y;
    t = __half22float2(h[2]); f[4] = t.x; f[5] = t.y;
    t = __half22float2(h[3]); f[6] = t.x; f[7] = t.y;
}

__device__ __forceinline__ uint4 pack8(const float* f) {
    union { uint4 u; __half2 h[4]; } v;
    v.h[0] = __floats2half2_rn(f[0], f[1]);
    v.h[1] = __floats2half2_rn(f[2], f[3]);
    v.h[2] = __floats2half2_rn(f[4], f[5]);
    v.h[3] = __floats2half2_rn(f[6], f[7]);
    return v.u;
}

__device__ __forceinline__ float deg2dinv(float dg) {
    return 1.0f / sqrtf(dg + 1.0f + 1e-8f);
}

// ---------------------------------------------------------------------------
// Kernel 1: token histogram -> masked mean embed -> fused X@w1+b1 -> M [N,16]
// ---------------------------------------------------------------------------
__global__ void encode_kernel(const int* __restrict__ seq,
                              const float* __restrict__ xcov,
                              const float* __restrict__ embed,   // 6x16 f32
                              const float* __restrict__ w1,      // 17x16 f32
                              const float* __restrict__ b1,      // 16 f32
                              float* __restrict__ M, int N) {
    __shared__ float sE[96];
    __shared__ float sW[272];
    __shared__ float sB[16];
    int tid = threadIdx.x;
    for (int i = tid; i < 96; i += BS) sE[i] = embed[i];
    for (int i = tid; i < 272; i += BS) sW[i] = w1[i];
    if (tid < 16) sB[tid] = b1[tid];
    __syncthreads();
    int n = blockIdx.x * BS + tid;
    if (n >= N) return;

    const int4* t4 = (const int4*)(seq + (size_t)n * 64);
    int c1 = 0, c2 = 0, c3 = 0, c4 = 0, c5 = 0;
#pragma unroll
    for (int i = 0; i < 16; i++) {
        int4 v = t4[i];
        c1 += (v.x == 1) + (v.y == 1) + (v.z == 1) + (v.w == 1);
        c2 += (v.x == 2) + (v.y == 2) + (v.z == 2) + (v.w == 2);
        c3 += (v.x == 3) + (v.y == 3) + (v.z == 3) + (v.w == 3);
        c4 += (v.x == 4) + (v.y == 4) + (v.z == 4) + (v.w == 4);
        c5 += (v.x == 5) + (v.y == 5) + (v.z == 5) + (v.w == 5);
    }
    float f1 = (float)c1, f2 = (float)c2, f3 = (float)c3, f4 = (float)c4, f5 = (float)c5;
    float tot = f1 + f2 + f3 + f4 + f5;
    float inv = 1.0f / fmaxf(tot, 1.0f);

    float h[16];
#pragma unroll
    for (int j = 0; j < 16; j++)
        h[j] = (f1 * sE[16 + j] + f2 * sE[32 + j] + f3 * sE[48 + j] +
                f4 * sE[64 + j] + f5 * sE[80 + j]) * inv;

    float xc = xcov[n];
    float o[16];
#pragma unroll
    for (int j = 0; j < 16; j++) o[j] = sB[j] + xc * sW[256 + j];
#pragma unroll
    for (int k = 0; k < 16; k++) {
        float hk = h[k];
#pragma unroll
        for (int j = 0; j < 16; j++) o[j] += hk * sW[k * 16 + j];
    }
    float4* mr = (float4*)(M + (size_t)n * 16);
    mr[0] = make_float4(o[0], o[1], o[2], o[3]);
    mr[1] = make_float4(o[4], o[5], o[6], o[7]);
    mr[2] = make_float4(o[8], o[9], o[10], o[11]);
    mr[3] = make_float4(o[12], o[13], o[14], o[15]);
}

// ---------------------------------------------------------------------------
// Kernel 2: prep — chunked compaction. LDS-local compaction per block, ONE
// global counter atomic per block (782 total, not 50k).
// ---------------------------------------------------------------------------
__global__ void prep_kernel(const int* __restrict__ ei,
                            const int* __restrict__ batch,
                            float* __restrict__ deg,
                            int2* __restrict__ list,
                            int* __restrict__ counter, int E) {
    __shared__ int2 buf[CHUNK];
    __shared__ int lcnt;
    __shared__ int base;
    int tid = threadIdx.x;
    if (tid == 0) lcnt = 0;
    __syncthreads();

    int e0 = blockIdx.x * CHUNK;
#pragma unroll
    for (int k = 0; k < CHUNK / BS; k++) {
        int e = e0 + k * BS + tid;
        if (e < E) {
            int s = ei[e];
            int d = ei[E + e];
            if (batch[s] == batch[d]) {
                atomicAdd(&deg[s], 1.0f);                 // distributed, cheap
                int pos = atomicAdd(&lcnt, 1);            // LDS atomic
                buf[pos] = make_int2(s, d);
            }
        }
    }
    __syncthreads();
    if (tid == 0) base = atomicAdd(counter, lcnt);        // 1 per block
    __syncthreads();
    int cnt = lcnt, b = base;
    for (int i = tid; i < cnt; i += BS) list[b + i] = buf[i];
}

// ---------------------------------------------------------------------------
// Kernel 3: message scatter over COMPACT list: agg[s] += dinv[d] * M[d]
// dinv computed on the fly from deg.
// ---------------------------------------------------------------------------
__global__ void agg_list_kernel(const int2* __restrict__ list,
                                const int* __restrict__ counter,
                                const float* __restrict__ deg,
                                const float* __restrict__ M,
                                float* __restrict__ agg) {
    int cnt = *counter;
    for (int i = blockIdx.x * BS + threadIdx.x; i < cnt; i += gridDim.x * BS) {
        int2 p = list[i];
        float c = deg2dinv(deg[p.y]);
        const float4* m4 = (const float4*)(M + (size_t)p.y * 16);
        float4 v0 = m4[0], v1 = m4[1], v2 = m4[2], v3 = m4[3];
        float* a = agg + (size_t)p.x * 16;
        atomicAdd(a + 0,  c * v0.x); atomicAdd(a + 1,  c * v0.y);
        atomicAdd(a + 2,  c * v0.z); atomicAdd(a + 3,  c * v0.w);
        atomicAdd(a + 4,  c * v1.x); atomicAdd(a + 5,  c * v1.y);
        atomicAdd(a + 6,  c * v1.z); atomicAdd(a + 7,  c * v1.w);
        atomicAdd(a + 8,  c * v2.x); atomicAdd(a + 9,  c * v2.y);
        atomicAdd(a + 10, c * v2.z); atomicAdd(a + 11, c * v2.w);
        atomicAdd(a + 12, c * v3.x); atomicAdd(a + 13, c * v3.y);
        atomicAdd(a + 14, c * v3.z); atomicAdd(a + 15, c * v3.w);
    }
}

// ---------------------------------------------------------------------------
// Kernel 4: H1 = relu(dinv*(agg + dinv*M)); M <- H1@w2+b2 (in place); agg <- 0
// ---------------------------------------------------------------------------
__global__ void finalize1_kernel(const float* __restrict__ deg,
                                 float* __restrict__ M,
                                 float* __restrict__ agg,
                                 const float* __restrict__ w2,
                                 const float* __restrict__ b2, int N) {
    __shared__ float sW[256];
    __shared__ float sB[16];
    int tid = threadIdx.x;
    for (int i = tid; i < 256; i += BS) sW[i] = w2[i];
    if (tid < 16) sB[tid] = b2[tid];
    __syncthreads();
    int n = blockIdx.x * BS + tid;
    if (n >= N) return;
    float di = deg2dinv(deg[n]);
    float4* mr = (float4*)(M + (size_t)n * 16);
    float4* ar = (float4*)(agg + (size_t)n * 16);
    float m[16], a[16];
    float4 t;
    t = mr[0]; m[0]=t.x; m[1]=t.y; m[2]=t.z; m[3]=t.w;
    t = mr[1]; m[4]=t.x; m[5]=t.y; m[6]=t.z; m[7]=t.w;
    t = mr[2]; m[8]=t.x; m[9]=t.y; m[10]=t.z; m[11]=t.w;
    t = mr[3]; m[12]=t.x; m[13]=t.y; m[14]=t.z; m[15]=t.w;
    t = ar[0]; a[0]=t.x; a[1]=t.y; a[2]=t.z; a[3]=t.w;
    t = ar[1]; a[4]=t.x; a[5]=t.y; a[6]=t.z; a[7]=t.w;
    t = ar[2]; a[8]=t.x; a[9]=t.y; a[10]=t.z; a[11]=t.w;
    t = ar[3]; a[12]=t.x; a[13]=t.y; a[14]=t.z; a[15]=t.w;
    // re-zero agg for layer 2
    float4 z = make_float4(0.f, 0.f, 0.f, 0.f);
    ar[0] = z; ar[1] = z; ar[2] = z; ar[3] = z;

    float h[16];
#pragma unroll
    for (int j = 0; j < 16; j++) h[j] = fmaxf(di * (a[j] + di * m[j]), 0.0f);

    float o[16];
#pragma unroll
    for (int j = 0; j < 16; j++) o[j] = sB[j];
#pragma unroll
    for (int k = 0; k < 16; k++) {
        float hk = h[k];
#pragma unroll
        for (int j = 0; j < 16; j++) o[j] += hk * sW[k * 16 + j];
    }
    mr[0] = make_float4(o[0], o[1], o[2], o[3]);
    mr[1] = make_float4(o[4], o[5], o[6], o[7]);
    mr[2] = make_float4(o[8], o[9], o[10], o[11]);
    mr[3] = make_float4(o[12], o[13], o[14], o[15]);
}

// ---------------------------------------------------------------------------
// Kernel 5: H2 = relu(dinv*(agg + dinv*M)); P = H2@we1[0:16]; Q = H2@we1[16:32]
// P, Q stored as f16 rows (32 B) for L2-resident gathers in edge MLP.
// ---------------------------------------------------------------------------
__global__ void finalize2_pq_kernel(const float* __restrict__ deg,
                                    const float* __restrict__ M,
                                    const float* __restrict__ agg,
                                    const float* __restrict__ we1,  // 37x16
                                    ushort* __restrict__ Pf,
                                    ushort* __restrict__ Qf, int N) {
    __shared__ float sW[512];   // we1 rows 0..31
    int tid = threadIdx.x;
    for (int i = tid; i < 512; i += BS) sW[i] = we1[i];
    __syncthreads();
    int n = blockIdx.x * BS + tid;
    if (n >= N) return;
    float di = deg2dinv(deg[n]);
    const float4* mr = (const float4*)(M + (size_t)n * 16);
    const float4* ar = (const float4*)(agg + (size_t)n * 16);
    float h[16];
#pragma unroll
    for (int q = 0; q < 4; q++) {
        float4 m = mr[q], a = ar[q];
        h[q*4+0] = fmaxf(di * (a.x + di * m.x), 0.0f);
        h[q*4+1] = fmaxf(di * (a.y + di * m.y), 0.0f);
        h[q*4+2] = fmaxf(di * (a.z + di * m.z), 0.0f);
        h[q*4+3] = fmaxf(di * (a.w + di * m.w), 0.0f);
    }
    float p[16], q[16];
#pragma unroll
    for (int j = 0; j < 16; j++) { p[j] = 0.f; q[j] = 0.f; }
#pragma unroll
    for (int k = 0; k < 16; k++) {
        float hk = h[k];
#pragma unroll
        for (int j = 0; j < 16; j++) {
            p[j] += hk * sW[k * 16 + j];
            q[j] += hk * sW[(16 + k) * 16 + j];
        }
    }
    uint4* pr = (uint4*)(Pf + (size_t)n * 16);
    pr[0] = pack8(p);
    pr[1] = pack8(p + 8);
    uint4* qr = (uint4*)(Qf + (size_t)n * 16);
    qr[0] = pack8(q);
    qr[1] = pack8(q + 8);
}

// ---------------------------------------------------------------------------
// Kernel 6: edge MLP via precomputed P/Q:
//   acc = P[s] + Q[d] + ea@C + be1 ; logit = relu(acc)@we2 + be2
// ---------------------------------------------------------------------------
__global__ void edge_mlp_kernel(const int* __restrict__ ei,
                                const ushort* __restrict__ Pf,
                                const ushort* __restrict__ Qf,
                                const float* __restrict__ eattr,   // E x 5 f32
                                const float* __restrict__ we1,     // 37x16 f32
                                const float* __restrict__ be1,     // 16
                                const float* __restrict__ we2,     // 16
                                const float* __restrict__ be2,     // 1
                                float* __restrict__ out, int E) {
    __shared__ float sC[80];   // we1 rows 32..36 (edge-attr block)
    __shared__ float sB[16];
    __shared__ float sV[16];
    __shared__ float sb2;
    int tid = threadIdx.x;
    if (tid < 80) sC[tid] = we1[512 + tid];
    if (tid < 16) { sB[tid] = be1[tid]; sV[tid] = we2[tid]; }
    if (tid == 0) sb2 = be2[0];
    __syncthreads();
    int e = blockIdx.x * BS + tid;
    if (e >= E) return;
    int s = ei[e];
    int d = ei[E + e];
    const uint4* pr = (const uint4*)(Pf + (size_t)s * 16);
    const uint4* qr = (const uint4*)(Qf + (size_t)d * 16);
    uint4 pa = pr[0], pb = pr[1];
    uint4 qa = qr[0], qb = qr[1];
    const float* ea = eattr + (size_t)e * 5;
    float a0 = ea[0], a1 = ea[1], a2 = ea[2], a3 = ea[3], a4 = ea[4];

    float p[16], q[16];
    unpack8(pa, p); unpack8(pb, p + 8);
    unpack8(qa, q); unpack8(qb, q + 8);

    float lg = sb2;
#pragma unroll
    for (int j = 0; j < 16; j++) {
        float acc = sB[j] + p[j] + q[j] +
                    a0 * sC[j] + a1 * sC[16 + j] + a2 * sC[32 + j] +
                    a3 * sC[48 + j] + a4 * sC[64 + j];
        lg += fmaxf(acc, 0.0f) * sV[j];
    }
    out[e] = lg;
}

// ---------------------------------------------------------------------------
extern "C" void kernel_launch(void* const* d_in, const int* in_sizes, int n_in,
                              void* d_out, int out_size, void* d_ws, size_t ws_size,
                              hipStream_t stream) {
    const int* seq     = (const int*)d_in[0];
    const float* xcov  = (const float*)d_in[1];
    const int* ei      = (const int*)d_in[2];
    const float* eattr = (const float*)d_in[3];
    const int* batch   = (const int*)d_in[4];
    const float* embed = (const float*)d_in[5];
    const float* w1    = (const float*)d_in[6];
    const float* b1    = (const float*)d_in[7];
    const float* w2    = (const float*)d_in[8];
    const float* b2    = (const float*)d_in[9];
    const float* we1   = (const float*)d_in[10];
    const float* be1   = (const float*)d_in[11];
    const float* we2   = (const float*)d_in[12];
    const float* be2   = (const float*)d_in[13];
    float* out         = (float*)d_out;   // fp32 output

    int N = in_sizes[1];
    int E = in_sizes[2] / 2;

    char* ws = (char*)d_ws;
    size_t off = 0;
    auto alloc = [&](size_t bytes) -> void* {
        void* p = ws + off;
        off += (bytes + 255) & ~(size_t)255;
        return p;
    };
    float* deg   = (float*)alloc((size_t)N * sizeof(float));
    float* M     = (float*)alloc((size_t)N * 16 * sizeof(float));
    float* agg   = (float*)alloc((size_t)N * 16 * sizeof(float));
    ushort* Pf   = (ushort*)alloc((size_t)N * 16 * sizeof(ushort));
    ushort* Qf   = (ushort*)alloc((size_t)N * 16 * sizeof(ushort));
    int* counter = (int*)alloc(sizeof(int));
    int2* list   = (int2*)alloc((size_t)E * sizeof(int2));         // worst case

    hipMemsetAsync(deg, 0, (size_t)N * sizeof(float), stream);
    hipMemsetAsync(agg, 0, (size_t)N * 16 * sizeof(float), stream);
    hipMemsetAsync(counter, 0, sizeof(int), stream);

    int gn = (N + BS - 1) / BS;
    int ge = (E + BS - 1) / BS;
    int gc = (E + CHUNK - 1) / CHUNK;

    encode_kernel<<<gn, BS, 0, stream>>>(seq, xcov, embed, w1, b1, M, N);
    prep_kernel<<<gc, BS, 0, stream>>>(ei, batch, deg, list, counter, E);
    agg_list_kernel<<<256, BS, 0, stream>>>(list, counter, deg, M, agg);
    finalize1_kernel<<<gn, BS, 0, stream>>>(deg, M, agg, w2, b2, N);
    agg_list_kernel<<<256, BS, 0, stream>>>(list, counter, deg, M, agg);
    finalize2_pq_kernel<<<gn, BS, 0, stream>>>(deg, M, agg, we1, Pf, Qf, N);
    edge_mlp_kernel<<<ge, BS, 0, stream>>>(ei, Pf, Qf, eattr, we1, be1, we2, be2, out, E);
}

// Round 6
// 369.100 us; speedup vs baseline: 1.8949x; 1.0274x over previous
//
#include <hip/hip_runtime.h>
#include <hip/hip_bf16.h>
#include <hip/hip_fp16.h>

#define BS 256
#define PCHUNK 2048   // edges per prep block: 256 threads x 4 edges x 2 iters

__device__ __forceinline__ void unpack8(uint4 u, float* f) {
    const __half2* h = (const __half2*)&u;
    float2 t;
    t = __half22float2(h[0]); f[0] = t.x; f[1] = t.y;
    t = __half22float2(h[1]); f[2] = t.x; f[3] = t.y;
    t = __half22float2(h[2]); f[4] = t.x; f[5] = t.y;
    t = __half22float2(h[3]); f[6] = t.x; f[7] = t.y;
}

__device__ __forceinline__ uint4 pack8(const float* f) {
    union { uint4 u; __half2 h[4]; } v;
    v.h[0] = __floats2half2_rn(f[0], f[1]);
    v.h[1] = __floats2half2_rn(f[2], f[3]);
    v.h[2] = __floats2half2_rn(f[4], f[5]);
    v.h[3] = __floats2half2_rn(f[6], f[7]);
    return v.u;
}

__device__ __forceinline__ float deg2dinv(float dg) {
    return 1.0f / sqrtf(dg + 1.0f + 1e-8f);
}

// ---------------------------------------------------------------------------
// Kernel 1: token histogram -> masked mean embed -> fused X@w1+b1 -> M [N,16]
// Also zeroes deg, agg, counter (replaces 3 memsets).
// ---------------------------------------------------------------------------
__global__ __launch_bounds__(BS) void encode_kernel(
        const int* __restrict__ seq,
        const float* __restrict__ xcov,
        const float* __restrict__ embed,   // 6x16 f32
        const float* __restrict__ w1,      // 17x16 f32
        const float* __restrict__ b1,      // 16 f32
        float* __restrict__ M,
        float* __restrict__ deg,
        float* __restrict__ agg,
        int* __restrict__ counter, int N) {
    __shared__ float sE[96];
    __shared__ float sW[272];
    __shared__ float sB[16];
    int tid = threadIdx.x;
    if (blockIdx.x == 0 && tid == 0) *counter = 0;
    for (int i = tid; i < 96; i += BS) sE[i] = embed[i];
    for (int i = tid; i < 272; i += BS) sW[i] = w1[i];
    if (tid < 16) sB[tid] = b1[tid];
    __syncthreads();
    int n = blockIdx.x * BS + tid;
    if (n >= N) return;

    deg[n] = 0.0f;
    float4 z = make_float4(0.f, 0.f, 0.f, 0.f);
    float4* ar = (float4*)(agg + (size_t)n * 16);
    ar[0] = z; ar[1] = z; ar[2] = z; ar[3] = z;

    const int4* t4 = (const int4*)(seq + (size_t)n * 64);
    int c1 = 0, c2 = 0, c3 = 0, c4 = 0, c5 = 0;
#pragma unroll
    for (int i = 0; i < 16; i++) {
        int4 v = t4[i];
        c1 += (v.x == 1) + (v.y == 1) + (v.z == 1) + (v.w == 1);
        c2 += (v.x == 2) + (v.y == 2) + (v.z == 2) + (v.w == 2);
        c3 += (v.x == 3) + (v.y == 3) + (v.z == 3) + (v.w == 3);
        c4 += (v.x == 4) + (v.y == 4) + (v.z == 4) + (v.w == 4);
        c5 += (v.x == 5) + (v.y == 5) + (v.z == 5) + (v.w == 5);
    }
    float f1 = (float)c1, f2 = (float)c2, f3 = (float)c3, f4 = (float)c4, f5 = (float)c5;
    float tot = f1 + f2 + f3 + f4 + f5;
    float inv = 1.0f / fmaxf(tot, 1.0f);

    float h[16];
#pragma unroll
    for (int j = 0; j < 16; j++)
        h[j] = (f1 * sE[16 + j] + f2 * sE[32 + j] + f3 * sE[48 + j] +
                f4 * sE[64 + j] + f5 * sE[80 + j]) * inv;

    float xc = xcov[n];
    float o[16];
#pragma unroll
    for (int j = 0; j < 16; j++) o[j] = sB[j] + xc * sW[256 + j];
#pragma unroll
    for (int k = 0; k < 16; k++) {
        float hk = h[k];
#pragma unroll
        for (int j = 0; j < 16; j++) o[j] += hk * sW[k * 16 + j];
    }
    float4* mr = (float4*)(M + (size_t)n * 16);
    mr[0] = make_float4(o[0], o[1], o[2], o[3]);
    mr[1] = make_float4(o[4], o[5], o[6], o[7]);
    mr[2] = make_float4(o[8], o[9], o[10], o[11]);
    mr[3] = make_float4(o[12], o[13], o[14], o[15]);
}

// ---------------------------------------------------------------------------
// Kernel 2: prep — vectorized (int4 = 4 edges/thread/iter), LDS compaction,
// one global counter atomic per block.
// ---------------------------------------------------------------------------
__global__ __launch_bounds__(BS) void prep_kernel(
        const int* __restrict__ ei,
        const int* __restrict__ batch,
        float* __restrict__ deg,
        int2* __restrict__ list,
        int* __restrict__ counter, int E) {
    __shared__ int2 buf[PCHUNK];
    __shared__ int lcnt;
    __shared__ int base;
    int tid = threadIdx.x;
    if (tid == 0) lcnt = 0;
    __syncthreads();

    int e0 = blockIdx.x * PCHUNK;
#pragma unroll
    for (int k = 0; k < PCHUNK / (BS * 4); k++) {
        int idx = e0 + (k * BS + tid) * 4;
        if (idx + 3 < E) {
            int4 s4 = *(const int4*)(ei + idx);
            int4 d4 = *(const int4*)(ei + E + idx);
            int bs0 = batch[s4.x], bd0 = batch[d4.x];
            int bs1 = batch[s4.y], bd1 = batch[d4.y];
            int bs2 = batch[s4.z], bd2 = batch[d4.z];
            int bs3 = batch[s4.w], bd3 = batch[d4.w];
            if (bs0 == bd0) { atomicAdd(&deg[s4.x], 1.0f); buf[atomicAdd(&lcnt, 1)] = make_int2(s4.x, d4.x); }
            if (bs1 == bd1) { atomicAdd(&deg[s4.y], 1.0f); buf[atomicAdd(&lcnt, 1)] = make_int2(s4.y, d4.y); }
            if (bs2 == bd2) { atomicAdd(&deg[s4.z], 1.0f); buf[atomicAdd(&lcnt, 1)] = make_int2(s4.z, d4.z); }
            if (bs3 == bd3) { atomicAdd(&deg[s4.w], 1.0f); buf[atomicAdd(&lcnt, 1)] = make_int2(s4.w, d4.w); }
        } else {
            for (int j = 0; j < 4; j++) {
                int e = idx + j;
                if (e < E) {
                    int s = ei[e], d = ei[E + e];
                    if (batch[s] == batch[d]) {
                        atomicAdd(&deg[s], 1.0f);
                        buf[atomicAdd(&lcnt, 1)] = make_int2(s, d);
                    }
                }
            }
        }
    }
    __syncthreads();
    if (tid == 0) base = atomicAdd(counter, lcnt);
    __syncthreads();
    int cnt = lcnt, b = base;
    for (int i = tid; i < cnt; i += BS) list[b + i] = buf[i];
}

// ---------------------------------------------------------------------------
// Kernel 3: message scatter over COMPACT list: agg[s] += dinv[d] * M[d]
// ---------------------------------------------------------------------------
__global__ __launch_bounds__(BS) void agg_list_kernel(
        const int2* __restrict__ list,
        const int* __restrict__ counter,
        const float* __restrict__ deg,
        const float* __restrict__ M,
        float* __restrict__ agg) {
    int cnt = *counter;
    for (int i = blockIdx.x * BS + threadIdx.x; i < cnt; i += gridDim.x * BS) {
        int2 p = list[i];
        float c = deg2dinv(deg[p.y]);
        const float4* m4 = (const float4*)(M + (size_t)p.y * 16);
        float4 v0 = m4[0], v1 = m4[1], v2 = m4[2], v3 = m4[3];
        float* a = agg + (size_t)p.x * 16;
        atomicAdd(a + 0,  c * v0.x); atomicAdd(a + 1,  c * v0.y);
        atomicAdd(a + 2,  c * v0.z); atomicAdd(a + 3,  c * v0.w);
        atomicAdd(a + 4,  c * v1.x); atomicAdd(a + 5,  c * v1.y);
        atomicAdd(a + 6,  c * v1.z); atomicAdd(a + 7,  c * v1.w);
        atomicAdd(a + 8,  c * v2.x); atomicAdd(a + 9,  c * v2.y);
        atomicAdd(a + 10, c * v2.z); atomicAdd(a + 11, c * v2.w);
        atomicAdd(a + 12, c * v3.x); atomicAdd(a + 13, c * v3.y);
        atomicAdd(a + 14, c * v3.z); atomicAdd(a + 15, c * v3.w);
    }
}

// ---------------------------------------------------------------------------
// Kernel 4: H1 = relu(dinv*(agg + dinv*M)); M <- H1@w2+b2 (in place); agg <- 0
// ---------------------------------------------------------------------------
__global__ __launch_bounds__(BS) void finalize1_kernel(
        const float* __restrict__ deg,
        float* __restrict__ M,
        float* __restrict__ agg,
        const float* __restrict__ w2,
        const float* __restrict__ b2, int N) {
    __shared__ float sW[256];
    __shared__ float sB[16];
    int tid = threadIdx.x;
    for (int i = tid; i < 256; i += BS) sW[i] = w2[i];
    if (tid < 16) sB[tid] = b2[tid];
    __syncthreads();
    int n = blockIdx.x * BS + tid;
    if (n >= N) return;
    float di = deg2dinv(deg[n]);
    float4* mr = (float4*)(M + (size_t)n * 16);
    float4* ar = (float4*)(agg + (size_t)n * 16);
    float m[16], a[16];
    float4 t;
    t = mr[0]; m[0]=t.x; m[1]=t.y; m[2]=t.z; m[3]=t.w;
    t = mr[1]; m[4]=t.x; m[5]=t.y; m[6]=t.z; m[7]=t.w;
    t = mr[2]; m[8]=t.x; m[9]=t.y; m[10]=t.z; m[11]=t.w;
    t = mr[3]; m[12]=t.x; m[13]=t.y; m[14]=t.z; m[15]=t.w;
    t = ar[0]; a[0]=t.x; a[1]=t.y; a[2]=t.z; a[3]=t.w;
    t = ar[1]; a[4]=t.x; a[5]=t.y; a[6]=t.z; a[7]=t.w;
    t = ar[2]; a[8]=t.x; a[9]=t.y; a[10]=t.z; a[11]=t.w;
    t = ar[3]; a[12]=t.x; a[13]=t.y; a[14]=t.z; a[15]=t.w;
    // re-zero agg for layer 2
    float4 z = make_float4(0.f, 0.f, 0.f, 0.f);
    ar[0] = z; ar[1] = z; ar[2] = z; ar[3] = z;

    float h[16];
#pragma unroll
    for (int j = 0; j < 16; j++) h[j] = fmaxf(di * (a[j] + di * m[j]), 0.0f);

    float o[16];
#pragma unroll
    for (int j = 0; j < 16; j++) o[j] = sB[j];
#pragma unroll
    for (int k = 0; k < 16; k++) {
        float hk = h[k];
#pragma unroll
        for (int j = 0; j < 16; j++) o[j] += hk * sW[k * 16 + j];
    }
    mr[0] = make_float4(o[0], o[1], o[2], o[3]);
    mr[1] = make_float4(o[4], o[5], o[6], o[7]);
    mr[2] = make_float4(o[8], o[9], o[10], o[11]);
    mr[3] = make_float4(o[12], o[13], o[14], o[15]);
}

// ---------------------------------------------------------------------------
// Kernel 5: H2 = relu(dinv*(agg + dinv*M)); P = H2@we1[0:16]; Q = H2@we1[16:32]
// P, Q stored as f16 rows (32 B) for L2-resident gathers in edge MLP.
// ---------------------------------------------------------------------------
__global__ __launch_bounds__(BS) void finalize2_pq_kernel(
        const float* __restrict__ deg,
        const float* __restrict__ M,
        const float* __restrict__ agg,
        const float* __restrict__ we1,  // 37x16
        ushort* __restrict__ Pf,
        ushort* __restrict__ Qf, int N) {
    __shared__ float sW[512];   // we1 rows 0..31
    int tid = threadIdx.x;
    for (int i = tid; i < 512; i += BS) sW[i] = we1[i];
    __syncthreads();
    int n = blockIdx.x * BS + tid;
    if (n >= N) return;
    float di = deg2dinv(deg[n]);
    const float4* mr = (const float4*)(M + (size_t)n * 16);
    const float4* ar = (const float4*)(agg + (size_t)n * 16);
    float h[16];
#pragma unroll
    for (int q = 0; q < 4; q++) {
        float4 m = mr[q], a = ar[q];
        h[q*4+0] = fmaxf(di * (a.x + di * m.x), 0.0f);
        h[q*4+1] = fmaxf(di * (a.y + di * m.y), 0.0f);
        h[q*4+2] = fmaxf(di * (a.z + di * m.z), 0.0f);
        h[q*4+3] = fmaxf(di * (a.w + di * m.w), 0.0f);
    }
    float p[16], q[16];
#pragma unroll
    for (int j = 0; j < 16; j++) { p[j] = 0.f; q[j] = 0.f; }
#pragma unroll
    for (int k = 0; k < 16; k++) {
        float hk = h[k];
#pragma unroll
        for (int j = 0; j < 16; j++) {
            p[j] += hk * sW[k * 16 + j];
            q[j] += hk * sW[(16 + k) * 16 + j];
        }
    }
    uint4* pr = (uint4*)(Pf + (size_t)n * 16);
    pr[0] = pack8(p);
    pr[1] = pack8(p + 8);
    uint4* qr = (uint4*)(Qf + (size_t)n * 16);
    qr[0] = pack8(q);
    qr[1] = pack8(q + 8);
}

// ---------------------------------------------------------------------------
// Kernel 6: edge MLP, 2 edges per thread, all gathers issued up front.
//   acc = P[s] + Q[d] + ea@C + be1 ; logit = relu(acc)@we2 + be2
// ---------------------------------------------------------------------------
__global__ __launch_bounds__(BS) void edge_mlp_kernel(
        const int* __restrict__ ei,
        const ushort* __restrict__ Pf,
        const ushort* __restrict__ Qf,
        const float* __restrict__ eattr,   // E x 5 f32
        const float* __restrict__ we1,     // 37x16 f32
        const float* __restrict__ be1,     // 16
        const float* __restrict__ we2,     // 16
        const float* __restrict__ be2,     // 1
        float* __restrict__ out, int E) {
    __shared__ float sC[80];   // we1 rows 32..36 (edge-attr block)
    __shared__ float sB[16];
    __shared__ float sV[16];
    __shared__ float sb2;
    int tid = threadIdx.x;
    if (tid < 80) sC[tid] = we1[512 + tid];
    if (tid < 16) { sB[tid] = be1[tid]; sV[tid] = we2[tid]; }
    if (tid == 0) sb2 = be2[0];
    __syncthreads();
    int base = (blockIdx.x * BS + tid) * 2;
    if (base >= E) return;
    bool two = (base + 1 < E);

    int2 ss = *(const int2*)(ei + base);
    int2 dd = *(const int2*)(ei + E + base);
    int s1 = two ? ss.y : ss.x, d1 = two ? dd.y : dd.x;

    // issue all 8 gathers up front
    const uint4* p0r = (const uint4*)(Pf + (size_t)ss.x * 16);
    const uint4* q0r = (const uint4*)(Qf + (size_t)dd.x * 16);
    const uint4* p1r = (const uint4*)(Pf + (size_t)s1 * 16);
    const uint4* q1r = (const uint4*)(Qf + (size_t)d1 * 16);
    uint4 pa0 = p0r[0], pb0 = p0r[1], qa0 = q0r[0], qb0 = q0r[1];
    uint4 pa1 = p1r[0], pb1 = p1r[1], qa1 = q1r[0], qb1 = q1r[1];

    // eattr for 2 consecutive edges: 10 floats, 8B-aligned -> 5 float2
    const float2* ea2 = (const float2*)(eattr + (size_t)base * 5);
    float2 t0 = ea2[0], t1 = ea2[1], t2 = ea2[2];
    float2 t3 = make_float2(0.f, 0.f), t4 = make_float2(0.f, 0.f);
    if (two) { t3 = ea2[3]; t4 = ea2[4]; }

    float p[16], q[16];
    unpack8(pa0, p); unpack8(pb0, p + 8);
    unpack8(qa0, q); unpack8(qb0, q + 8);
    float lg0 = sb2;
#pragma unroll
    for (int j = 0; j < 16; j++) {
        float acc = sB[j] + p[j] + q[j] +
                    t0.x * sC[j] + t0.y * sC[16 + j] + t1.x * sC[32 + j] +
                    t1.y * sC[48 + j] + t2.x * sC[64 + j];
        lg0 += fmaxf(acc, 0.0f) * sV[j];
    }

    unpack8(pa1, p); unpack8(pb1, p + 8);
    unpack8(qa1, q); unpack8(qb1, q + 8);
    float lg1 = sb2;
#pragma unroll
    for (int j = 0; j < 16; j++) {
        float acc = sB[j] + p[j] + q[j] +
                    t2.y * sC[j] + t3.x * sC[16 + j] + t3.y * sC[32 + j] +
                    t4.x * sC[48 + j] + t4.y * sC[64 + j];
        lg1 += fmaxf(acc, 0.0f) * sV[j];
    }

    if (two) {
        *(float2*)(out + base) = make_float2(lg0, lg1);
    } else {
        out[base] = lg0;
    }
}

// ---------------------------------------------------------------------------
extern "C" void kernel_launch(void* const* d_in, const int* in_sizes, int n_in,
                              void* d_out, int out_size, void* d_ws, size_t ws_size,
                              hipStream_t stream) {
    const int* seq     = (const int*)d_in[0];
    const float* xcov  = (const float*)d_in[1];
    const int* ei      = (const int*)d_in[2];
    const float* eattr = (const float*)d_in[3];
    const int* batch   = (const int*)d_in[4];
    const float* embed = (const float*)d_in[5];
    const float* w1    = (const float*)d_in[6];
    const float* b1    = (const float*)d_in[7];
    const float* w2    = (const float*)d_in[8];
    const float* b2    = (const float*)d_in[9];
    const float* we1   = (const float*)d_in[10];
    const float* be1   = (const float*)d_in[11];
    const float* we2   = (const float*)d_in[12];
    const float* be2   = (const float*)d_in[13];
    float* out         = (float*)d_out;   // fp32 output

    int N = in_sizes[1];
    int E = in_sizes[2] / 2;

    char* ws = (char*)d_ws;
    size_t off = 0;
    auto alloc = [&](size_t bytes) -> void* {
        void* p = ws + off;
        off += (bytes + 255) & ~(size_t)255;
        return p;
    };
    float* deg   = (float*)alloc((size_t)N * sizeof(float));
    float* M     = (float*)alloc((size_t)N * 16 * sizeof(float));
    float* agg   = (float*)alloc((size_t)N * 16 * sizeof(float));
    ushort* Pf   = (ushort*)alloc((size_t)N * 16 * sizeof(ushort));
    ushort* Qf   = (ushort*)alloc((size_t)N * 16 * sizeof(ushort));
    int* counter = (int*)alloc(sizeof(int));
    int2* list   = (int2*)alloc((size_t)E * sizeof(int2));         // worst case

    int gn  = (N + BS - 1) / BS;
    int gc  = (E + PCHUNK - 1) / PCHUNK;
    int ge2 = (E / 2 + BS - 1) / BS;

    encode_kernel<<<gn, BS, 0, stream>>>(seq, xcov, embed, w1, b1, M, deg, agg, counter, N);
    prep_kernel<<<gc, BS, 0, stream>>>(ei, batch, deg, list, counter, E);
    agg_list_kernel<<<256, BS, 0, stream>>>(list, counter, deg, M, agg);
    finalize1_kernel<<<gn, BS, 0, stream>>>(deg, M, agg, w2, b2, N);
    agg_list_kernel<<<256, BS, 0, stream>>>(list, counter, deg, M, agg);
    finalize2_pq_kernel<<<gn, BS, 0, stream>>>(deg, M, agg, we1, Pf, Qf, N);
    edge_mlp_kernel<<<ge2, BS, 0, stream>>>(ei, Pf, Qf, eattr, we1, be1, we2, be2, out, E);
}

// Round 7
// 358.552 us; speedup vs baseline: 1.9507x; 1.0294x over previous
//
#include <hip/hip_runtime.h>
#include <hip/hip_bf16.h>
#include <hip/hip_fp16.h>

#define BS 256
#define PCHUNK 2048   // edges per prep block
#define NG 64         // NUM_GRAPHS (fixed by the problem)

__device__ __forceinline__ void unpack8(uint4 u, float* f) {
    const __half2* h = (const __half2*)&u;
    float2 t;
    t = __half22float2(h[0]); f[0] = t.x; f[1] = t.y;
    t = __half22float2(h[1]); f[2] = t.x; f[3] = t.y;
    t = __half22float2(h[2]); f[4] = t.x; f[5] = t.y;
    t = __half22float2(h[3]); f[6] = t.x; f[7] = t.y;
}

__device__ __forceinline__ uint4 pack8(const float* f) {
    union { uint4 u; __half2 h[4]; } v;
    v.h[0] = __floats2half2_rn(f[0], f[1]);
    v.h[1] = __floats2half2_rn(f[2], f[3]);
    v.h[2] = __floats2half2_rn(f[4], f[5]);
    v.h[3] = __floats2half2_rn(f[6], f[7]);
    return v.u;
}

__device__ __forceinline__ float deg2dinv(float dg) {
    return 1.0f / sqrtf(dg + 1.0f + 1e-8f);
}

// ---------------------------------------------------------------------------
// Kernel 0: graph boundaries from sorted batch. bnd[g] = #nodes with batch<g,
// g in [0, NG]; so nodes of graph g occupy [bnd[g], bnd[g+1]).
// ---------------------------------------------------------------------------
__global__ __launch_bounds__(BS) void bounds_kernel(
        const int* __restrict__ batch, int* __restrict__ bnd, int N) {
    int n = blockIdx.x * BS + threadIdx.x;
    if (n >= N) return;
    int b = batch[n];
    if (n == 0) {
        for (int g = 0; g <= b; g++) bnd[g] = 0;
    } else {
        int pb = batch[n - 1];
        for (int g = pb + 1; g <= b; g++) bnd[g] = n;
    }
    if (n == N - 1) {
        for (int g = b + 1; g <= NG; g++) bnd[g] = N;
    }
}

// ---------------------------------------------------------------------------
// Kernel 1: token histogram -> masked mean embed -> fused X@w1+b1 -> M [N,16]
// Also zeroes deg, agg, counter (replaces 3 memsets).
// ---------------------------------------------------------------------------
__global__ __launch_bounds__(BS) void encode_kernel(
        const int* __restrict__ seq,
        const float* __restrict__ xcov,
        const float* __restrict__ embed,   // 6x16 f32
        const float* __restrict__ w1,      // 17x16 f32
        const float* __restrict__ b1,      // 16 f32
        float* __restrict__ M,
        float* __restrict__ deg,
        float* __restrict__ agg,
        int* __restrict__ counter, int N) {
    __shared__ float sE[96];
    __shared__ float sW[272];
    __shared__ float sB[16];
    int tid = threadIdx.x;
    if (blockIdx.x == 0 && tid == 0) *counter = 0;
    for (int i = tid; i < 96; i += BS) sE[i] = embed[i];
    for (int i = tid; i < 272; i += BS) sW[i] = w1[i];
    if (tid < 16) sB[tid] = b1[tid];
    __syncthreads();
    int n = blockIdx.x * BS + tid;
    if (n >= N) return;

    deg[n] = 0.0f;
    float4 z = make_float4(0.f, 0.f, 0.f, 0.f);
    float4* ar = (float4*)(agg + (size_t)n * 16);
    ar[0] = z; ar[1] = z; ar[2] = z; ar[3] = z;

    const int4* t4 = (const int4*)(seq + (size_t)n * 64);
    int c1 = 0, c2 = 0, c3 = 0, c4 = 0, c5 = 0;
#pragma unroll
    for (int i = 0; i < 16; i++) {
        int4 v = t4[i];
        c1 += (v.x == 1) + (v.y == 1) + (v.z == 1) + (v.w == 1);
        c2 += (v.x == 2) + (v.y == 2) + (v.z == 2) + (v.w == 2);
        c3 += (v.x == 3) + (v.y == 3) + (v.z == 3) + (v.w == 3);
        c4 += (v.x == 4) + (v.y == 4) + (v.z == 4) + (v.w == 4);
        c5 += (v.x == 5) + (v.y == 5) + (v.z == 5) + (v.w == 5);
    }
    float f1 = (float)c1, f2 = (float)c2, f3 = (float)c3, f4 = (float)c4, f5 = (float)c5;
    float tot = f1 + f2 + f3 + f4 + f5;
    float inv = 1.0f / fmaxf(tot, 1.0f);

    float h[16];
#pragma unroll
    for (int j = 0; j < 16; j++)
        h[j] = (f1 * sE[16 + j] + f2 * sE[32 + j] + f3 * sE[48 + j] +
                f4 * sE[64 + j] + f5 * sE[80 + j]) * inv;

    float xc = xcov[n];
    float o[16];
#pragma unroll
    for (int j = 0; j < 16; j++) o[j] = sB[j] + xc * sW[256 + j];
#pragma unroll
    for (int k = 0; k < 16; k++) {
        float hk = h[k];
#pragma unroll
        for (int j = 0; j < 16; j++) o[j] += hk * sW[k * 16 + j];
    }
    float4* mr = (float4*)(M + (size_t)n * 16);
    mr[0] = make_float4(o[0], o[1], o[2], o[3]);
    mr[1] = make_float4(o[4], o[5], o[6], o[7]);
    mr[2] = make_float4(o[8], o[9], o[10], o[11]);
    mr[3] = make_float4(o[12], o[13], o[14], o[15]);
}

// ---------------------------------------------------------------------------
// Kernel 2: prep — validity by LDS binary search on graph bounds (no batch
// gathers), int4-vectorized ei reads, LDS compaction, 1 counter atomic/block.
// ---------------------------------------------------------------------------
__device__ __forceinline__ int find_graph(const int* bnd, int s) {
    int g = 0;
#pragma unroll
    for (int step = 32; step; step >>= 1) {
        int c = g + step;
        if (c <= NG - 1 && bnd[c] <= s) g = c;
    }
    return g;
}

__global__ __launch_bounds__(BS) void prep_kernel(
        const int* __restrict__ ei,
        const int* __restrict__ bndg,     // NG+1 ints
        float* __restrict__ deg,
        int2* __restrict__ list,
        int* __restrict__ counter, int E) {
    __shared__ int2 buf[PCHUNK];
    __shared__ int sBnd[NG + 1];
    __shared__ int lcnt;
    __shared__ int base;
    int tid = threadIdx.x;
    if (tid == 0) lcnt = 0;
    if (tid <= NG) sBnd[tid] = bndg[tid];
    __syncthreads();

    int e0 = blockIdx.x * PCHUNK;
#pragma unroll
    for (int k = 0; k < PCHUNK / (BS * 4); k++) {
        int idx = e0 + (k * BS + tid) * 4;
        if (idx + 3 < E) {
            int4 s4 = *(const int4*)(ei + idx);
            int4 d4 = *(const int4*)(ei + E + idx);
#pragma unroll
            for (int j = 0; j < 4; j++) {
                int s = (&s4.x)[j], d = (&d4.x)[j];
                int g = find_graph(sBnd, s);
                if (d >= sBnd[g] && d < sBnd[g + 1]) {
                    atomicAdd(&deg[s], 1.0f);
                    buf[atomicAdd(&lcnt, 1)] = make_int2(s, d);
                }
            }
        } else {
            for (int j = 0; j < 4; j++) {
                int e = idx + j;
                if (e < E) {
                    int s = ei[e], d = ei[E + e];
                    int g = find_graph(sBnd, s);
                    if (d >= sBnd[g] && d < sBnd[g + 1]) {
                        atomicAdd(&deg[s], 1.0f);
                        buf[atomicAdd(&lcnt, 1)] = make_int2(s, d);
                    }
                }
            }
        }
    }
    __syncthreads();
    if (tid == 0) base = atomicAdd(counter, lcnt);
    __syncthreads();
    int cnt = lcnt, b = base;
    for (int i = tid; i < cnt; i += BS) list[b + i] = buf[i];
}

// ---------------------------------------------------------------------------
// Kernel 3: message scatter over COMPACT list: agg[s] += dinv[d] * M[d]
// ---------------------------------------------------------------------------
__global__ __launch_bounds__(BS) void agg_list_kernel(
        const int2* __restrict__ list,
        const int* __restrict__ counter,
        const float* __restrict__ deg,
        const float* __restrict__ M,
        float* __restrict__ agg) {
    int cnt = *counter;
    for (int i = blockIdx.x * BS + threadIdx.x; i < cnt; i += gridDim.x * BS) {
        int2 p = list[i];
        float c = deg2dinv(deg[p.y]);
        const float4* m4 = (const float4*)(M + (size_t)p.y * 16);
        float4 v0 = m4[0], v1 = m4[1], v2 = m4[2], v3 = m4[3];
        float* a = agg + (size_t)p.x * 16;
        atomicAdd(a + 0,  c * v0.x); atomicAdd(a + 1,  c * v0.y);
        atomicAdd(a + 2,  c * v0.z); atomicAdd(a + 3,  c * v0.w);
        atomicAdd(a + 4,  c * v1.x); atomicAdd(a + 5,  c * v1.y);
        atomicAdd(a + 6,  c * v1.z); atomicAdd(a + 7,  c * v1.w);
        atomicAdd(a + 8,  c * v2.x); atomicAdd(a + 9,  c * v2.y);
        atomicAdd(a + 10, c * v2.z); atomicAdd(a + 11, c * v2.w);
        atomicAdd(a + 12, c * v3.x); atomicAdd(a + 13, c * v3.y);
        atomicAdd(a + 14, c * v3.z); atomicAdd(a + 15, c * v3.w);
    }
}

// ---------------------------------------------------------------------------
// Kernel 4: H1 = relu(dinv*(agg + dinv*M)); M <- H1@w2+b2 (in place); agg <- 0
// ---------------------------------------------------------------------------
__global__ __launch_bounds__(BS) void finalize1_kernel(
        const float* __restrict__ deg,
        float* __restrict__ M,
        float* __restrict__ agg,
        const float* __restrict__ w2,
        const float* __restrict__ b2, int N) {
    __shared__ float sW[256];
    __shared__ float sB[16];
    int tid = threadIdx.x;
    for (int i = tid; i < 256; i += BS) sW[i] = w2[i];
    if (tid < 16) sB[tid] = b2[tid];
    __syncthreads();
    int n = blockIdx.x * BS + tid;
    if (n >= N) return;
    float di = deg2dinv(deg[n]);
    float4* mr = (float4*)(M + (size_t)n * 16);
    float4* ar = (float4*)(agg + (size_t)n * 16);
    float m[16], a[16];
    float4 t;
    t = mr[0]; m[0]=t.x; m[1]=t.y; m[2]=t.z; m[3]=t.w;
    t = mr[1]; m[4]=t.x; m[5]=t.y; m[6]=t.z; m[7]=t.w;
    t = mr[2]; m[8]=t.x; m[9]=t.y; m[10]=t.z; m[11]=t.w;
    t = mr[3]; m[12]=t.x; m[13]=t.y; m[14]=t.z; m[15]=t.w;
    t = ar[0]; a[0]=t.x; a[1]=t.y; a[2]=t.z; a[3]=t.w;
    t = ar[1]; a[4]=t.x; a[5]=t.y; a[6]=t.z; a[7]=t.w;
    t = ar[2]; a[8]=t.x; a[9]=t.y; a[10]=t.z; a[11]=t.w;
    t = ar[3]; a[12]=t.x; a[13]=t.y; a[14]=t.z; a[15]=t.w;
    // re-zero agg for layer 2
    float4 z = make_float4(0.f, 0.f, 0.f, 0.f);
    ar[0] = z; ar[1] = z; ar[2] = z; ar[3] = z;

    float h[16];
#pragma unroll
    for (int j = 0; j < 16; j++) h[j] = fmaxf(di * (a[j] + di * m[j]), 0.0f);

    float o[16];
#pragma unroll
    for (int j = 0; j < 16; j++) o[j] = sB[j];
#pragma unroll
    for (int k = 0; k < 16; k++) {
        float hk = h[k];
#pragma unroll
        for (int j = 0; j < 16; j++) o[j] += hk * sW[k * 16 + j];
    }
    mr[0] = make_float4(o[0], o[1], o[2], o[3]);
    mr[1] = make_float4(o[4], o[5], o[6], o[7]);
    mr[2] = make_float4(o[8], o[9], o[10], o[11]);
    mr[3] = make_float4(o[12], o[13], o[14], o[15]);
}

// ---------------------------------------------------------------------------
// Kernel 5: H2 = relu(dinv*(agg + dinv*M)); P = H2@we1[0:16]; Q = H2@we1[16:32]
// P, Q stored as f16 rows (32 B) for gathers in edge MLP.
// ---------------------------------------------------------------------------
__global__ __launch_bounds__(BS) void finalize2_pq_kernel(
        const float* __restrict__ deg,
        const float* __restrict__ M,
        const float* __restrict__ agg,
        const float* __restrict__ we1,  // 37x16
        ushort* __restrict__ Pf,
        ushort* __restrict__ Qf, int N) {
    __shared__ float sW[512];   // we1 rows 0..31
    int tid = threadIdx.x;
    for (int i = tid; i < 512; i += BS) sW[i] = we1[i];
    __syncthreads();
    int n = blockIdx.x * BS + tid;
    if (n >= N) return;
    float di = deg2dinv(deg[n]);
    const float4* mr = (const float4*)(M + (size_t)n * 16);
    const float4* ar = (const float4*)(agg + (size_t)n * 16);
    float h[16];
#pragma unroll
    for (int q = 0; q < 4; q++) {
        float4 m = mr[q], a = ar[q];
        h[q*4+0] = fmaxf(di * (a.x + di * m.x), 0.0f);
        h[q*4+1] = fmaxf(di * (a.y + di * m.y), 0.0f);
        h[q*4+2] = fmaxf(di * (a.z + di * m.z), 0.0f);
        h[q*4+3] = fmaxf(di * (a.w + di * m.w), 0.0f);
    }
    float p[16], q[16];
#pragma unroll
    for (int j = 0; j < 16; j++) { p[j] = 0.f; q[j] = 0.f; }
#pragma unroll
    for (int k = 0; k < 16; k++) {
        float hk = h[k];
#pragma unroll
        for (int j = 0; j < 16; j++) {
            p[j] += hk * sW[k * 16 + j];
            q[j] += hk * sW[(16 + k) * 16 + j];
        }
    }
    uint4* pr = (uint4*)(Pf + (size_t)n * 16);
    pr[0] = pack8(p);
    pr[1] = pack8(p + 8);
    uint4* qr = (uint4*)(Qf + (size_t)n * 16);
    qr[0] = pack8(q);
    qr[1] = pack8(q + 8);
}

// ---------------------------------------------------------------------------
// Kernel 6: edge MLP (R5 form — 1 edge/thread, 32 VGPR, high occupancy):
//   acc = P[s] + Q[d] + ea@C + be1 ; logit = relu(acc)@we2 + be2
// ---------------------------------------------------------------------------
__global__ __launch_bounds__(BS) void edge_mlp_kernel(
        const int* __restrict__ ei,
        const ushort* __restrict__ Pf,
        const ushort* __restrict__ Qf,
        const float* __restrict__ eattr,   // E x 5 f32
        const float* __restrict__ we1,     // 37x16 f32
        const float* __restrict__ be1,     // 16
        const float* __restrict__ we2,     // 16
        const float* __restrict__ be2,     // 1
        float* __restrict__ out, int E) {
    __shared__ float sC[80];   // we1 rows 32..36 (edge-attr block)
    __shared__ float sB[16];
    __shared__ float sV[16];
    __shared__ float sb2;
    int tid = threadIdx.x;
    if (tid < 80) sC[tid] = we1[512 + tid];
    if (tid < 16) { sB[tid] = be1[tid]; sV[tid] = we2[tid]; }
    if (tid == 0) sb2 = be2[0];
    __syncthreads();
    int e = blockIdx.x * BS + tid;
    if (e >= E) return;
    int s = ei[e];
    int d = ei[E + e];
    const uint4* pr = (const uint4*)(Pf + (size_t)s * 16);
    const uint4* qr = (const uint4*)(Qf + (size_t)d * 16);
    uint4 pa = pr[0], pb = pr[1];
    uint4 qa = qr[0], qb = qr[1];
    const float* ea = eattr + (size_t)e * 5;
    float a0 = ea[0], a1 = ea[1], a2 = ea[2], a3 = ea[3], a4 = ea[4];

    float p[16], q[16];
    unpack8(pa, p); unpack8(pb, p + 8);
    unpack8(qa, q); unpack8(qb, q + 8);

    float lg = sb2;
#pragma unroll
    for (int j = 0; j < 16; j++) {
        float acc = sB[j] + p[j] + q[j] +
                    a0 * sC[j] + a1 * sC[16 + j] + a2 * sC[32 + j] +
                    a3 * sC[48 + j] + a4 * sC[64 + j];
        lg += fmaxf(acc, 0.0f) * sV[j];
    }
    out[e] = lg;
}

// ---------------------------------------------------------------------------
extern "C" void kernel_launch(void* const* d_in, const int* in_sizes, int n_in,
                              void* d_out, int out_size, void* d_ws, size_t ws_size,
                              hipStream_t stream) {
    const int* seq     = (const int*)d_in[0];
    const float* xcov  = (const float*)d_in[1];
    const int* ei      = (const int*)d_in[2];
    const float* eattr = (const float*)d_in[3];
    const int* batch   = (const int*)d_in[4];
    const float* embed = (const float*)d_in[5];
    const float* w1    = (const float*)d_in[6];
    const float* b1    = (const float*)d_in[7];
    const float* w2    = (const float*)d_in[8];
    const float* b2    = (const float*)d_in[9];
    const float* we1   = (const float*)d_in[10];
    const float* be1   = (const float*)d_in[11];
    const float* we2   = (const float*)d_in[12];
    const float* be2   = (const float*)d_in[13];
    float* out         = (float*)d_out;   // fp32 output

    int N = in_sizes[1];
    int E = in_sizes[2] / 2;

    char* ws = (char*)d_ws;
    size_t off = 0;
    auto alloc = [&](size_t bytes) -> void* {
        void* p = ws + off;
        off += (bytes + 255) & ~(size_t)255;
        return p;
    };
    float* deg   = (float*)alloc((size_t)N * sizeof(float));
    float* M     = (float*)alloc((size_t)N * 16 * sizeof(float));
    float* agg   = (float*)alloc((size_t)N * 16 * sizeof(float));
    ushort* Pf   = (ushort*)alloc((size_t)N * 16 * sizeof(ushort));
    ushort* Qf   = (ushort*)alloc((size_t)N * 16 * sizeof(ushort));
    int* counter = (int*)alloc(sizeof(int));
    int* bndg    = (int*)alloc((NG + 1) * sizeof(int));
    int2* list   = (int2*)alloc((size_t)E * sizeof(int2));         // worst case

    int gn  = (N + BS - 1) / BS;
    int gc  = (E + PCHUNK - 1) / PCHUNK;
    int ge  = (E + BS - 1) / BS;

    bounds_kernel<<<gn, BS, 0, stream>>>(batch, bndg, N);
    encode_kernel<<<gn, BS, 0, stream>>>(seq, xcov, embed, w1, b1, M, deg, agg, counter, N);
    prep_kernel<<<gc, BS, 0, stream>>>(ei, bndg, deg, list, counter, E);
    agg_list_kernel<<<256, BS, 0, stream>>>(list, counter, deg, M, agg);
    finalize1_kernel<<<gn, BS, 0, stream>>>(deg, M, agg, w2, b2, N);
    agg_list_kernel<<<256, BS, 0, stream>>>(list, counter, deg, M, agg);
    finalize2_pq_kernel<<<gn, BS, 0, stream>>>(deg, M, agg, we1, Pf, Qf, N);
    edge_mlp_kernel<<<ge, BS, 0, stream>>>(ei, Pf, Qf, eattr, we1, be1, we2, be2, out, E);
}